// Round 3
// baseline (244.220 us; speedup 1.0000x reference)
//
#include <hip/hip_runtime.h>
#include <stdint.h>

// out[b,s,d] = x[b,s,d] + pe[s,d]   (fp32 in/out)
//   pe[s,d] = (d even) ? sin(s * 10000^(-2d/1024)) : cos(s * 10000^(-2d/1024))
// Shape (8, 4096, 1024). Min traffic: 134 MB read + 134 MB write.
//
// R2 post-mortem: VGPR_Count stayed 32 => compiler SANK the 8 loads back into
// the store loop (register-pressure scheduling), recreating the serialized
// load->store chain (1.9 TB/s, 102 us). Fix: hard-enforce the phase split:
//   - sched_barrier(0) after the load loop: no instruction may cross, so all
//     8 global_load_dwordx4 issue before any store.
//   - asm keep-alive on each x[b]: defeats rematerialization/sinking.
// In-order vmcnt retirement then lets each add wait only on its own load;
// stores never gate loads. 8 KB/wave in flight (vs 1 KB) -> latency hidden.
//
// Load policy: cached (R1/R2: L2/L3 serve half the input, FETCH 65.5 MB).
// Store policy: nontemporal (write-once stream; don't thrash input from L3).
// PE math bit-identical to the passing kernel (absmax unchanged).

constexpr int MODEL_DIM = 1024;
constexpr int SEQ = 4096;
constexpr int BATCH = 8;
constexpr int SD = SEQ * MODEL_DIM;           // 4,194,304
constexpr float C_FREQ = -0.025952563241307517f;  // -log2(10000)/512

typedef float v4f __attribute__((ext_vector_type(4)));

__global__ __launch_bounds__(256) void pe_add_kernel(
    const float* __restrict__ xin, float* __restrict__ xout)
{
    const int t = blockIdx.x * blockDim.x + threadIdx.x;  // 0 .. SD/4-1
    const int s = t >> 8;                 // 256 float4 vectors per seq position
    const int dbase = (t & 255) << 2;     // starting dim, multiple of 4 (even)

    const size_t base = (size_t)t * 4;

    // Phase 1: issue ALL batch loads back-to-back (loads-only vmcnt chain).
    v4f x[BATCH];
#pragma unroll
    for (int b = 0; b < BATCH; ++b)
        x[b] = *(const v4f*)(xin + (size_t)b * (size_t)SD + base);

    // Keep every loaded value live + forbid any code motion across this point.
#pragma unroll
    for (int b = 0; b < BATCH; ++b)
        asm volatile("" : "+v"(x[b]));
    __builtin_amdgcn_sched_barrier(0);

    // Phase 2: PE compute (VALU-only) — runs while the loads are in flight.
    const float pos = (float)s;
    float pe[4];
#pragma unroll
    for (int j = 0; j < 4; ++j) {
        const float angle = pos * exp2f(C_FREQ * (float)(dbase + j));
        pe[j] = (j & 1) ? cosf(angle) : sinf(angle);  // accurate range reduction
    }
    v4f pv;
    pv.x = pe[0]; pv.y = pe[1]; pv.z = pe[2]; pv.w = pe[3];

    // Phase 3: add + store in load order (in-order completion => each add's
    // waitcnt is satisfied exactly when its own load returns).
#pragma unroll
    for (int b = 0; b < BATCH; ++b) {
        v4f y = x[b] + pv;
        __builtin_nontemporal_store(y, (v4f*)(xout + (size_t)b * (size_t)SD + base));
    }
}

extern "C" void kernel_launch(void* const* d_in, const int* in_sizes, int n_in,
                              void* d_out, int out_size, void* d_ws, size_t ws_size,
                              hipStream_t stream) {
    const float* x = (const float*)d_in[0];
    float* out = (float*)d_out;
    const int threads = 256;
    const int blocks = (SD / 4) / threads;   // 4096 blocks, exact cover
    pe_add_kernel<<<blocks, threads, 0, stream>>>(x, out);
}

// Round 4
// 242.322 us; speedup vs baseline: 1.0078x; 1.0078x over previous
//
#include <hip/hip_runtime.h>
#include <stdint.h>

// out[b,s,d] = x[b,s,d] + pe[s,d]   (fp32 in/out)
//   pe[s,d] = (d even) ? sin(s * 10000^(-2d/1024)) : cos(s * 10000^(-2d/1024))
// Shape (8, 4096, 1024). Min traffic: 134 MB read + 134 MB write.
//
// R3 post-mortem: VGPR_Count stayed 32 across THREE attempts to hoist the 8
// batch loads at HIP level — the compiler always re-sinks them into the store
// loop (register-minimal schedule), coupling each load's vmcnt wait to the
// previous NT store's drain => ~3 KB/CU in flight, 2.6 TB/s delivered, 102 us.
//
// R4 fix: pin the memory pipeline with inline asm (volatile asms are strictly
// ordered among themselves):
//     L0..L7, [W0 S0 W1 S1 ... W7 S7],  Wb = s_waitcnt vmcnt(7)
// At Wb exactly 7 VMEM ops are younger than load b (7-b loads + b stores), so
// vmcnt(7) retires load b and NEVER waits on a store. The add is data-tied to
// the waitcnt asm via "+v"(x[b]) (rule-#18-proof: consumer depends on the
// waitcnt itself). 8 KB/wave in flight -> latency hidden.
//
// Load policy: cached (R1-R3: L2/L3 serve half the input, FETCH 65.5 MB).
// Store policy: nt (write-once stream; don't thrash the input out of L3).
// PE math bit-identical to the passing kernel (absmax unchanged).

constexpr int MODEL_DIM = 1024;
constexpr int SEQ = 4096;
constexpr int BATCH = 8;
constexpr int SD = SEQ * MODEL_DIM;           // 4,194,304 elements per batch
constexpr float C_FREQ = -0.025952563241307517f;  // -log2(10000)/512

typedef float v4f __attribute__((ext_vector_type(4)));

__global__ __launch_bounds__(256) void pe_add_kernel(
    const float* __restrict__ xin, float* __restrict__ xout)
{
    const int t = blockIdx.x * blockDim.x + threadIdx.x;  // 0 .. SD/4-1
    const int s = t >> 8;                 // 256 float4 vectors per seq position
    const int dbase = (t & 255) << 2;     // starting dim, multiple of 4 (even)

    // Per-lane byte offset of this thread's float4 within one batch image.
    // Max voffset = byte0 + 7*SD*4 = 134 MB < 2^32: SGPR-base+voffset form ok.
    const uint32_t byte0 = (uint32_t)t * 16u;

    // ---- Phase 1: issue ALL 8 loads back-to-back (pinned by volatile asm).
    v4f x[BATCH];
#pragma unroll
    for (int b = 0; b < BATCH; ++b) {
        const uint32_t voff = byte0 + (uint32_t)b * (uint32_t)(SD * 4);
        asm volatile("global_load_dwordx4 %0, %1, %2"
                     : "=v"(x[b])
                     : "v"(voff), "s"(xin));
    }

    // ---- Phase 2: PE compute (VALU-only) overlaps the loads in flight.
    const float pos = (float)s;
    float pe[4];
#pragma unroll
    for (int j = 0; j < 4; ++j) {
        const float angle = pos * exp2f(C_FREQ * (float)(dbase + j));
        pe[j] = (j & 1) ? cosf(angle) : sinf(angle);  // accurate range reduction
    }
    v4f pv;
    pv.x = pe[0]; pv.y = pe[1]; pv.z = pe[2]; pv.w = pe[3];

    // ---- Phase 3: counted consume. vmcnt(7) retires exactly load b
    // (7 younger VMEM ops: 7-b loads + b stores) and never waits on a store.
#pragma unroll
    for (int b = 0; b < BATCH; ++b) {
        asm volatile("s_waitcnt vmcnt(7)" : "+v"(x[b]));
        v4f y = x[b] + pv;
        const uint32_t voff = byte0 + (uint32_t)b * (uint32_t)(SD * 4);
        asm volatile("global_store_dwordx4 %0, %1, %2 nt"
                     :: "v"(voff), "v"(y), "s"(xout));
    }
}

extern "C" void kernel_launch(void* const* d_in, const int* in_sizes, int n_in,
                              void* d_out, int out_size, void* d_ws, size_t ws_size,
                              hipStream_t stream) {
    const float* x = (const float*)d_in[0];
    float* out = (float*)d_out;
    const int threads = 256;
    const int blocks = (SD / 4) / threads;   // 4096 blocks, exact cover
    pe_add_kernel<<<blocks, threads, 0, stream>>>(x, out);
}

// Round 5
// 240.909 us; speedup vs baseline: 1.0137x; 1.0059x over previous
//
#include <hip/hip_runtime.h>
#include <stdint.h>

// out[b,s,d] = x[b,s,d] + pe[s,d]   (fp32 in/out)
//   pe[s,d] = (d even) ? sin(s * 10000^(-2d/1024)) : cos(s * 10000^(-2d/1024))
// Shape (8, 4096, 1024). Min traffic: 134 MB read + 134 MB write.
//
// R4 post-mortem: pinned-asm 8-deep pipeline (VGPR 36, counted vmcnt) changed
// NOTHING vs the compiler's serialized schedule => latency/MLP was never the
// bottleneck (TLP alone suffices: ~17 waves/CU x 1KB >> Little's-law need).
// The policy matrix is the signal:
//   NT load  + NT store  : ~85 us   (R0)
//   cached   + NT store  : ~100 us  (R1-R4)  <- NT stores are the poison
//   cached   + cached    : THIS KERNEL
// Harness fillBufferAligned (cached stores, write-only) sustains 6.7 TB/s --
// proof the cached-store path streams at ~85% of peak with full-line write
// combining. Theory: NT stores bypass L2 and mix with reads at the HBM
// interface (read/write turnaround), back-pressuring the VMEM pipe; cached
// stores are absorbed by L2 and written back in bursts. Cached loads keep the
// L3 input service (FETCH 65 MB, half the reads never touch HBM).
//
// PE math bit-identical to the passing kernel (absmax unchanged).

constexpr int MODEL_DIM = 1024;
constexpr int SEQ = 4096;
constexpr int BATCH = 8;
constexpr int SD = SEQ * MODEL_DIM;           // 4,194,304 elements per batch
constexpr float C_FREQ = -0.025952563241307517f;  // -log2(10000)/512

typedef float v4f __attribute__((ext_vector_type(4)));

__global__ __launch_bounds__(256) void pe_add_kernel(
    const float* __restrict__ xin, float* __restrict__ xout)
{
    const int t = blockIdx.x * blockDim.x + threadIdx.x;  // 0 .. SD/4-1
    const int s = t >> 8;                 // 256 float4 vectors per seq position
    const int dbase = (t & 255) << 2;     // starting dim, multiple of 4 (even)

    // PE computed once per 32 output elements (amortized over 8 batches).
    const float pos = (float)s;
    float pe[4];
#pragma unroll
    for (int j = 0; j < 4; ++j) {
        const float angle = pos * exp2f(C_FREQ * (float)(dbase + j));
        pe[j] = (j & 1) ? cosf(angle) : sinf(angle);  // accurate range reduction
    }
    v4f pv;
    pv.x = pe[0]; pv.y = pe[1]; pv.z = pe[2]; pv.w = pe[3];

    const size_t base = (size_t)t * 4;
#pragma unroll
    for (int b = 0; b < BATCH; ++b) {
        const size_t off = (size_t)b * (size_t)SD + base;
        v4f x = *(const v4f*)(xin + off);   // cached: L3-resident input
        x += pv;
        *(v4f*)(xout + off) = x;            // cached: L2-absorbed write stream
    }
}

extern "C" void kernel_launch(void* const* d_in, const int* in_sizes, int n_in,
                              void* d_out, int out_size, void* d_ws, size_t ws_size,
                              hipStream_t stream) {
    const float* x = (const float*)d_in[0];
    float* out = (float*)d_out;
    const int threads = 256;
    const int blocks = (SD / 4) / threads;   // 4096 blocks, exact cover
    pe_add_kernel<<<blocks, threads, 0, stream>>>(x, out);
}

// Round 6
// 234.427 us; speedup vs baseline: 1.0418x; 1.0276x over previous
//
#include <hip/hip_runtime.h>
#include <stdint.h>

// out[b,s,d] = x[b,s,d] + pe[s,d]   (fp32 in/out)
//   pe[s,d] = (d even) ? sin(s * 10000^(-2d/1024)) : cos(s * 10000^(-2d/1024))
// Shape (8, 4096, 1024). Traffic: 134 MB read + 134 MB write.
//
// R6 = exact revert to the R0 kernel (NT loads + NT stores), the best-measured
// configuration (dur_us 230.0; kernel below the 79.5 us fill cutoff in rocprof).
// The completed policy matrix over R0-R5:
//   NT/NT <= 79.5 us | cached/NT ~100 us | cached/cached ~100 us
// => cached LOADS are the poison (+20 us regardless of store policy); store
// policy and load/store scheduling (R4 pinned-asm pipeline) are both neutral.
// Mechanism: nt loads take the streaming bypass; allocating loads add L2
// alloc/backpressure overhead that outweighs the 65 MB of cache hits.
//
// PE per-thread: one float4 of dims at one s, looped over all 8 batches
// (4 sin/cos pairs amortized 8x). PE math bit-identical (absmax 0.03125).

constexpr int MODEL_DIM = 1024;
constexpr int SEQ = 4096;
constexpr int BATCH = 8;
constexpr int SD = SEQ * MODEL_DIM;           // 4,194,304
constexpr float C_FREQ = -0.025952563241307517f;  // -log2(10000)/512

typedef float v4f __attribute__((ext_vector_type(4)));

__global__ __launch_bounds__(256) void pe_add_kernel(
    const float* __restrict__ xin, float* __restrict__ xout)
{
    const int t = blockIdx.x * blockDim.x + threadIdx.x;  // 0 .. SD/4-1
    const int s = t >> 8;                 // 256 float4 vectors per seq position
    const int dbase = (t & 255) << 2;     // starting dim, multiple of 4 (even)

    const float pos = (float)s;
    float pe[4];
#pragma unroll
    for (int j = 0; j < 4; ++j) {
        const float angle = pos * exp2f(C_FREQ * (float)(dbase + j));
        pe[j] = (j & 1) ? cosf(angle) : sinf(angle);  // accurate range reduction
    }
    v4f pv;
    pv.x = pe[0]; pv.y = pe[1]; pv.z = pe[2]; pv.w = pe[3];

    const size_t base = (size_t)t * 4;
#pragma unroll
    for (int b = 0; b < BATCH; ++b) {
        const size_t off = (size_t)b * (size_t)SD + base;
        v4f x = __builtin_nontemporal_load((const v4f*)(xin + off));  // read-once
        x += pv;
        __builtin_nontemporal_store(x, (v4f*)(xout + off));           // write-only
    }
}

extern "C" void kernel_launch(void* const* d_in, const int* in_sizes, int n_in,
                              void* d_out, int out_size, void* d_ws, size_t ws_size,
                              hipStream_t stream) {
    const float* x = (const float*)d_in[0];
    float* out = (float*)d_out;
    const int threads = 256;
    const int blocks = (SD / 4) / threads;   // 4096 blocks, exact cover
    pe_add_kernel<<<blocks, threads, 0, stream>>>(x, out);
}

// Round 7
// 231.556 us; speedup vs baseline: 1.0547x; 1.0124x over previous
//
#include <hip/hip_runtime.h>
#include <stdint.h>

// out[b,s,d] = x[b,s,d] + pe[s,d]   (fp32 in/out)
//   pe[s,d] = (d even) ? sin(s * 10000^(-2d/1024)) : cos(s * 10000^(-2d/1024))
// Shape (8, 4096, 1024). Traffic: 134 MB read + 134 MB write.
//
// Policy matrix (kernel time, measured R0-R6):
//   NT/NT    : <79.3 us  (best; R0/R6)
//   cached/NT: ~100 us   (cached loads poison: L2 alloc overhead > hit benefit)
//   cached/cached: ~100 us
//   NT/cached: THIS KERNEL (last untested cell)
// Rationale: with NT loads nothing allocates into L2, so the full 32 MB L2 is
// a write-combining buffer for the output stream. The harness fill proves the
// cached-store path sustains 6.7 TB/s (84% peak). If NT/NT's residual gap to
// the 43 us floor is NT stores mixing read/write at the HBM interface, cached
// stores should close part of it. One-variable change vs best-known config.
//
// PE per-thread: one float4 of dims at one s, looped over all 8 batches
// (4 sin/cos pairs amortized 8x). PE math bit-identical (absmax 0.03125).

constexpr int MODEL_DIM = 1024;
constexpr int SEQ = 4096;
constexpr int BATCH = 8;
constexpr int SD = SEQ * MODEL_DIM;           // 4,194,304
constexpr float C_FREQ = -0.025952563241307517f;  // -log2(10000)/512

typedef float v4f __attribute__((ext_vector_type(4)));

__global__ __launch_bounds__(256) void pe_add_kernel(
    const float* __restrict__ xin, float* __restrict__ xout)
{
    const int t = blockIdx.x * blockDim.x + threadIdx.x;  // 0 .. SD/4-1
    const int s = t >> 8;                 // 256 float4 vectors per seq position
    const int dbase = (t & 255) << 2;     // starting dim, multiple of 4 (even)

    const float pos = (float)s;
    float pe[4];
#pragma unroll
    for (int j = 0; j < 4; ++j) {
        const float angle = pos * exp2f(C_FREQ * (float)(dbase + j));
        pe[j] = (j & 1) ? cosf(angle) : sinf(angle);  // accurate range reduction
    }
    v4f pv;
    pv.x = pe[0]; pv.y = pe[1]; pv.z = pe[2]; pv.w = pe[3];

    const size_t base = (size_t)t * 4;
#pragma unroll
    for (int b = 0; b < BATCH; ++b) {
        const size_t off = (size_t)b * (size_t)SD + base;
        v4f x = __builtin_nontemporal_load((const v4f*)(xin + off));  // non-allocating read
        x += pv;
        *(v4f*)(xout + off) = x;   // cached store: L2 write-combining path
    }
}

extern "C" void kernel_launch(void* const* d_in, const int* in_sizes, int n_in,
                              void* d_out, int out_size, void* d_ws, size_t ws_size,
                              hipStream_t stream) {
    const float* x = (const float*)d_in[0];
    float* out = (float*)d_out;
    const int threads = 256;
    const int blocks = (SD / 4) / threads;   // 4096 blocks, exact cover
    pe_add_kernel<<<blocks, threads, 0, stream>>>(x, out);
}